// Round 6
// baseline (1846.656 us; speedup 1.0000x reference)
//
#include <hip/hip_runtime.h>

#define E_TOTAL 50000
#define NTILES  3125      // E_TOTAL / 16, exact

// ---- workspace map (bytes) ----
#define EK_B  524288ull                      // 3125 * 4096  = 12.8 MB (packed s4v ek)
#define EM_B  (EK_B + 12800000ull)           // 12.8 MB (packed s4v em)
#define SK_B  (EM_B + 12800000ull)           // 3 * 12.8 MB (silu'd K-path B-frags)
#define SM_B  (SK_B + 38400000ull)           // 3 * 12.8 MB
#define WS_NEED (SM_B + 38400000ull)         // ~103 MB

typedef float f4  __attribute__((ext_vector_type(4)));
typedef short s8v __attribute__((ext_vector_type(8)));   // 8 bf16 bit-patterns (4 VGPRs)
typedef short s4v __attribute__((ext_vector_type(4)));   // 4 bf16 bit-patterns (2 VGPRs)

typedef __attribute__((address_space(3))) unsigned lds_u32;
typedef __attribute__((address_space(1))) const unsigned g_u32;

__device__ __forceinline__ short f2bf(float x){
  unsigned u = __builtin_bit_cast(unsigned, x);
  u += 0x7fffu + ((u >> 16) & 1u);           // RNE
  return (short)(u >> 16);
}
__device__ __forceinline__ float bf2f(short s){
  unsigned u = ((unsigned)(unsigned short)s) << 16;
  return __builtin_bit_cast(float, u);
}
__device__ __forceinline__ float sigm(float x){ return 1.f/(1.f + __expf(-x)); }

__device__ __forceinline__ s8v load_bfrag(const float* p){
  f4 a = *(const f4*)p;
  f4 b = *(const f4*)(p + 4);
  s8v r;
  r[0]=f2bf(a[0]); r[1]=f2bf(a[1]); r[2]=f2bf(a[2]); r[3]=f2bf(a[3]);
  r[4]=f2bf(b[0]); r[5]=f2bf(b[1]); r[6]=f2bf(b[2]); r[7]=f2bf(b[3]);
  return r;
}

// D[128 features x 16 edges] += A(from LDS, static base) @ B
__device__ __forceinline__ void mm8l(f4* acc, const s8v* B, const s8v* A, int lane){
  #pragma unroll
  for (int mb = 0; mb < 8; ++mb){
    #pragma unroll
    for (int kk = 0; kk < 4; ++kk){
      s8v af = A[(mb*4 + kk)*64 + lane];
      acc[mb] = __builtin_amdgcn_mfma_f32_16x16x32_bf16(af, B[kk], acc[mb], 0, 0, 0);
    }
  }
}

// Cooperative 32KB matrix stage for 256 threads: 8 iters x 16B/thread.
__device__ __forceinline__ void stage_mat(const short* __restrict__ src,
                                          short* dst, int wid, int lane){
  #pragma unroll
  for (int j = 0; j < 8; ++j){
    const short* gsrc = src + j*2048 + wid*512 + lane*8;
    short* ldst = dst + j*2048 + wid*512;
    __builtin_amdgcn_global_load_lds((g_u32*)(const void*)gsrc, (lds_u32*)(void*)ldst, 16, 0, 0);
  }
}

// ---------------------------------------------------------------------------
// Precompute: 14 fragment-ready bf16 A-matrices (A[m][k] = W[k][m], optionally
// W = X@Y fused product), packed so lane reads 16B contiguous per (mblk,kk).
//   mi 0 WqT(nat) | 1 GKT=Wk@Wk1a | 2 GMT=Wv@Wm1a | 3 GKaT=We@Wk1c | 4 GMaT=We@Wm1c
//   mi 5 Wk2T(dlay) | 6 Wm2T(dlay) | 7 WcT(dlay) | 8..10 GKeT[t] | 11..13 GMeT[t]
// ---------------------------------------------------------------------------
__global__ __launch_bounds__(256) void pack_weights(
    const float* __restrict__ Wq, const float* __restrict__ Wk, const float* __restrict__ Wv,
    const float* __restrict__ Wke, const float* __restrict__ Wve, const float* __restrict__ We,
    const float* __restrict__ Wc, const float* __restrict__ Wk1, const float* __restrict__ Wk2,
    const float* __restrict__ Wm1, const float* __restrict__ Wm2,
    short* __restrict__ wsm)
{
  int mi   = blockIdx.x >> 6;
  int elem = ((blockIdx.x & 63) << 8) + threadIdx.x;   // 0..16383
  int p  = elem & 7;
  int l  = (elem >> 3) & 63;
  int kk = (elem >> 9) & 3;
  int mb = elem >> 11;
  int gg = l >> 4;
  int m  = mb*16 + (l & 15);
  bool dlay = (mi == 5) || (mi == 6) || (mi == 7);
  int k = dlay ? (kk*32 + ((p < 4) ? (gg*4 + p) : (16 + gg*4 + (p - 4))))
               : (kk*32 + gg*8 + p);

  const float* X = nullptr; const float* Y = nullptr; const float* W = nullptr;
  switch (mi){
    case 0: W = Wq; break;
    case 1: X = Wk; Y = Wk1;            break;
    case 2: X = Wv; Y = Wm1;            break;
    case 3: X = We; Y = Wk1 + 256*128;  break;
    case 4: X = We; Y = Wm1 + 256*128;  break;
    case 5: W = Wk2; break;
    case 6: W = Wm2; break;
    case 7: W = Wc;  break;
    default:
      if (mi < 11){ X = Wke + (mi-8)*16384;  Y = Wk1 + 128*128; }
      else        { X = Wve + (mi-11)*16384; Y = Wm1 + 128*128; }
  }
  float v;
  if (W){
    v = W[k*128 + m];
  } else {
    v = 0.f;
    for (int j = 0; j < 128; ++j) v += X[k*128 + j] * Y[j*128 + m];
  }
  wsm[(size_t)mi*16384 + elem] = f2bf(v);
}

// biasK[t] = bk@Wk1a + bke[t]@Wk1b + bk1 ; biasM[t] = bv@Wm1a + bve[t]@Wm1b + bm1
__global__ __launch_bounds__(128) void make_biases(
    const float* __restrict__ bk,  const float* __restrict__ bke, const float* __restrict__ bk1,
    const float* __restrict__ bv,  const float* __restrict__ bve, const float* __restrict__ bm1,
    const float* __restrict__ Wk1, const float* __restrict__ Wm1,
    float* __restrict__ wsb)
{
  int b = blockIdx.x;          // 0..2 -> biasK[t], 3..5 -> biasM[t]
  int t = b % 3;
  bool isM = b >= 3;
  int o = threadIdx.x;
  const float* W  = isM ? Wm1 : Wk1;
  const float* b0 = isM ? bv  : bk;
  const float* be = (isM ? bve : bke) + t*128;
  const float* b1 = isM ? bm1 : bk1;
  float v = b1[o];
  for (int j = 0; j < 128; ++j)
    v += b0[j]*W[j*128 + o] + be[j]*W[(128 + j)*128 + o];
  wsb[b*128 + o] = v;
}

// ---------------------------------------------------------------------------
// K1: ek = edge@GK, em = edge@GM. Weights persistent in LDS (64KB, 2 blk/CU).
// Barrier-free tile loop; outputs packed s4v (the exact register format the
// consumer re-loads).
// ---------------------------------------------------------------------------
__global__ __launch_bounds__(256) void k_proj(
    const float* __restrict__ edge, const short* __restrict__ wsm,
    char* __restrict__ ws)
{
  __shared__ short lds[2*16384];
  const int lane = threadIdx.x & 63;
  const int wid  = threadIdx.x >> 6;
  stage_mat(wsm + 1*16384, lds,         wid, lane);   // GK
  stage_mat(wsm + 2*16384, lds + 16384, wid, lane);   // GM
  __syncthreads();
  const int g = lane >> 4, er = lane & 15;

  for (int tile = blockIdx.x; tile < NTILES; tile += gridDim.x){
    const size_t e = (size_t)tile*16 + er;
    const float* erow = edge + e*128;
    s8v BE[4];
    #pragma unroll
    for (int kk = 0; kk < 4; ++kk) BE[kk] = load_bfrag(erow + kk*32 + g*8);

    f4 acc[8];
    #pragma unroll
    for (int mb = 0; mb < 8; ++mb){ f4 z = {0.f,0.f,0.f,0.f}; acc[mb] = z; }
    mm8l(acc, BE, (const s8v*)lds, lane);
    #pragma unroll
    for (int mb = 0; mb < 8; ++mb){
      s4v t4; t4[0]=f2bf(acc[mb][0]); t4[1]=f2bf(acc[mb][1]); t4[2]=f2bf(acc[mb][2]); t4[3]=f2bf(acc[mb][3]);
      *(s4v*)(ws + EK_B + (size_t)tile*4096 + mb*512 + lane*8) = t4;
    }
    #pragma unroll
    for (int mb = 0; mb < 8; ++mb){ f4 z = {0.f,0.f,0.f,0.f}; acc[mb] = z; }
    mm8l(acc, BE, (const s8v*)(lds + 16384), lane);
    #pragma unroll
    for (int mb = 0; mb < 8; ++mb){
      s4v t4; t4[0]=f2bf(acc[mb][0]); t4[1]=f2bf(acc[mb][1]); t4[2]=f2bf(acc[mb][2]); t4[3]=f2bf(acc[mb][3]);
      *(s4v*)(ws + EM_B + (size_t)tile*4096 + mb*512 + lane*8) = t4;
    }
  }
}

// ---------------------------------------------------------------------------
// K2 (grid.y = t): h1K = ek + L@GKe[t] + A@GKa + biasK[t]; SK = silu(h1K)
//                  h1M = em + L@GMe[t] + A@GMa + biasM[t]; SM = silu(h1M)
// Weights persistent in LDS (128KB). L/A fragments loaded once, shared by
// both paths. Outputs in B-fragment (s8v) layout for K3's GEMMs.
// ---------------------------------------------------------------------------
__global__ __launch_bounds__(256) void k_mid(
    const float* __restrict__ nlen, const float* __restrict__ nang,
    const short* __restrict__ wsm, const float* __restrict__ wsb,
    char* __restrict__ ws)
{
  __shared__ short lds[4*16384];
  const int lane = threadIdx.x & 63;
  const int wid  = threadIdx.x >> 6;
  const int t    = blockIdx.y;
  stage_mat(wsm + (size_t)(8 + t)*16384, lds,          wid, lane);  // GKe[t]
  stage_mat(wsm + 3*16384,               lds + 16384,  wid, lane);  // GKa
  stage_mat(wsm + (size_t)(11 + t)*16384, lds + 32768, wid, lane);  // GMe[t]
  stage_mat(wsm + 4*16384,               lds + 49152,  wid, lane);  // GMa
  __syncthreads();
  const int g = lane >> 4, er = lane & 15;
  const float* biasK = wsb + t*128;
  const float* biasM = wsb + 384 + t*128;

  for (int tile = blockIdx.x; tile < NTILES; tile += gridDim.x){
    const size_t e = (size_t)tile*16 + er;
    const float* lrow = nlen + (e*3 + t)*128;
    const float* arow = nang + (e*3 + t)*128;
    s8v BL[4], BA[4];
    #pragma unroll
    for (int kk = 0; kk < 4; ++kk){
      BL[kk] = load_bfrag(lrow + kk*32 + g*8);
      BA[kk] = load_bfrag(arow + kk*32 + g*8);
    }

    f4 acc[8];
    // ---- K path ----
    #pragma unroll
    for (int mb = 0; mb < 8; ++mb){
      f4 b = *(const f4*)(biasK + mb*16 + g*4);
      s4v ek = *(const s4v*)(ws + EK_B + (size_t)tile*4096 + mb*512 + lane*8);
      #pragma unroll
      for (int r = 0; r < 4; ++r) b[r] += bf2f(ek[r]);
      acc[mb] = b;
    }
    mm8l(acc, BL, (const s8v*)lds, lane);
    mm8l(acc, BA, (const s8v*)(lds + 16384), lane);
    #pragma unroll
    for (int kk = 0; kk < 4; ++kk){
      s8v S;
      #pragma unroll
      for (int p = 0; p < 4; ++p){
        float x0 = acc[2*kk][p];   S[p]   = f2bf(x0 * sigm(x0));
        float x1 = acc[2*kk+1][p]; S[4+p] = f2bf(x1 * sigm(x1));
      }
      *(s8v*)(ws + SK_B + ((size_t)(t*NTILES + tile))*4096 + kk*1024 + lane*16) = S;
    }
    // ---- M path ----
    #pragma unroll
    for (int mb = 0; mb < 8; ++mb){
      f4 b = *(const f4*)(biasM + mb*16 + g*4);
      s4v em = *(const s4v*)(ws + EM_B + (size_t)tile*4096 + mb*512 + lane*8);
      #pragma unroll
      for (int r = 0; r < 4; ++r) b[r] += bf2f(em[r]);
      acc[mb] = b;
    }
    mm8l(acc, BL, (const s8v*)(lds + 32768), lane);
    mm8l(acc, BA, (const s8v*)(lds + 49152), lane);
    #pragma unroll
    for (int kk = 0; kk < 4; ++kk){
      s8v S;
      #pragma unroll
      for (int p = 0; p < 4; ++p){
        float x0 = acc[2*kk][p];   S[p]   = f2bf(x0 * sigm(x0));
        float x1 = acc[2*kk+1][p]; S[4+p] = f2bf(x1 * sigm(x1));
      }
      *(s8v*)(ws + SM_B + ((size_t)(t*NTILES + tile))*4096 + kk*1024 + lane*16) = S;
    }
  }
}

// ---------------------------------------------------------------------------
// K3: q = edge@Wq + bq; per t: alpha = q .* (SK@Wk2 + bk2)/sqrt(C); LN; gate;
// gm += gate .* (SM@Wm2 + bm2); out = softplus(edge + LN(gm@Wc + 3bc)).
// Weights persistent in LDS (128KB). Barrier-free tile loop.
// ---------------------------------------------------------------------------
__global__ __launch_bounds__(256) void k_fin(
    const float* __restrict__ edge,
    const float* __restrict__ bq,  const float* __restrict__ bk2, const float* __restrict__ bm2,
    const float* __restrict__ bc,
    const float* __restrict__ g_att, const float* __restrict__ b_att,
    const float* __restrict__ g_bn,  const float* __restrict__ b_bn,
    const short* __restrict__ wsm, const char* __restrict__ ws,
    float* __restrict__ out)
{
  __shared__ short lds[4*16384];
  const int lane = threadIdx.x & 63;
  const int wid  = threadIdx.x >> 6;
  stage_mat(wsm + 0*16384, lds,          wid, lane);  // Wq
  stage_mat(wsm + 5*16384, lds + 16384,  wid, lane);  // Wk2 (dlay)
  stage_mat(wsm + 6*16384, lds + 32768,  wid, lane);  // Wm2 (dlay)
  stage_mat(wsm + 7*16384, lds + 49152,  wid, lane);  // Wc  (dlay)
  __syncthreads();
  const int g = lane >> 4, er = lane & 15;

  for (int tile = blockIdx.x; tile < NTILES; tile += gridDim.x){
    const size_t e = (size_t)tile*16 + er;
    const float* erow = edge + e*128;
    s8v BE[4];
    #pragma unroll
    for (int kk = 0; kk < 4; ++kk) BE[kk] = load_bfrag(erow + kk*32 + g*8);

    f4 qf[8], gm[8], acc[8], gate[8];
    #pragma unroll
    for (int mb = 0; mb < 8; ++mb) qf[mb] = *(const f4*)(bq + mb*16 + g*4);
    mm8l(qf, BE, (const s8v*)lds, lane);
    #pragma unroll
    for (int mb = 0; mb < 8; ++mb){ f4 z = {0.f,0.f,0.f,0.f}; gm[mb] = z; }

    #pragma unroll 1
    for (int t = 0; t < 3; ++t){
      s8v SF[4];
      #pragma unroll
      for (int kk = 0; kk < 4; ++kk)
        SF[kk] = *(const s8v*)(ws + SK_B + ((size_t)(t*NTILES + tile))*4096 + kk*1024 + lane*16);
      #pragma unroll
      for (int mb = 0; mb < 8; ++mb) acc[mb] = *(const f4*)(bk2 + mb*16 + g*4);
      mm8l(acc, SF, (const s8v*)(lds + 16384), lane);

      float sm = 0.f, ssq = 0.f;
      #pragma unroll
      for (int mb = 0; mb < 8; ++mb){
        #pragma unroll
        for (int r = 0; r < 4; ++r){
          float a = qf[mb][r] * acc[mb][r] * 0.08838834764831845f;
          acc[mb][r] = a; sm += a; ssq += a*a;
        }
      }
      sm  += __shfl_xor(sm, 16);  sm  += __shfl_xor(sm, 32);
      ssq += __shfl_xor(ssq, 16); ssq += __shfl_xor(ssq, 32);
      float mean = sm * (1.f/128.f);
      float rstd = rsqrtf(ssq * (1.f/128.f) - mean*mean + 1e-5f);
      #pragma unroll
      for (int mb = 0; mb < 8; ++mb){
        f4 ga = *(const f4*)(g_att + mb*16 + g*4);
        f4 bb = *(const f4*)(b_att + mb*16 + g*4);
        #pragma unroll
        for (int r = 0; r < 4; ++r)
          gate[mb][r] = sigm((acc[mb][r] - mean)*rstd*ga[r] + bb[r]);
      }

      #pragma unroll
      for (int kk = 0; kk < 4; ++kk)
        SF[kk] = *(const s8v*)(ws + SM_B + ((size_t)(t*NTILES + tile))*4096 + kk*1024 + lane*16);
      #pragma unroll
      for (int mb = 0; mb < 8; ++mb) acc[mb] = *(const f4*)(bm2 + mb*16 + g*4);
      mm8l(acc, SF, (const s8v*)(lds + 32768), lane);
      #pragma unroll
      for (int mb = 0; mb < 8; ++mb){
        #pragma unroll
        for (int r = 0; r < 4; ++r) gm[mb][r] += acc[mb][r] * gate[mb][r];
      }
    }

    // out = softplus(edge + LN(gm@Wc + 3bc))
    s8v GF[4];
    #pragma unroll
    for (int kk = 0; kk < 4; ++kk){
      #pragma unroll
      for (int p = 0; p < 4; ++p){
        GF[kk][p]   = f2bf(gm[2*kk][p]);
        GF[kk][4+p] = f2bf(gm[2*kk+1][p]);
      }
    }
    #pragma unroll
    for (int mb = 0; mb < 8; ++mb){
      f4 b = *(const f4*)(bc + mb*16 + g*4);
      #pragma unroll
      for (int r = 0; r < 4; ++r) b[r] *= 3.f;
      acc[mb] = b;
    }
    mm8l(acc, GF, (const s8v*)(lds + 49152), lane);

    float sm = 0.f, ssq = 0.f;
    #pragma unroll
    for (int mb = 0; mb < 8; ++mb){
      #pragma unroll
      for (int r = 0; r < 4; ++r){ sm += acc[mb][r]; ssq += acc[mb][r]*acc[mb][r]; }
    }
    sm  += __shfl_xor(sm, 16);  sm  += __shfl_xor(sm, 32);
    ssq += __shfl_xor(ssq, 16); ssq += __shfl_xor(ssq, 32);
    float mean = sm * (1.f/128.f);
    float rstd = rsqrtf(ssq * (1.f/128.f) - mean*mean + 1e-5f);

    #pragma unroll
    for (int mb = 0; mb < 8; ++mb){
      f4 ev  = *(const f4*)(erow + mb*16 + g*4);
      f4 gv  = *(const f4*)(g_bn + mb*16 + g*4);
      f4 bv2 = *(const f4*)(b_bn + mb*16 + g*4);
      f4 o;
      #pragma unroll
      for (int r = 0; r < 4; ++r){
        float x = ev[r] + (acc[mb][r] - mean)*rstd*gv[r] + bv2[r];
        o[r] = (x > 20.f) ? x : log1pf(__expf(x));
      }
      *(f4*)(out + e*128 + mb*16 + g*4) = o;
    }
  }
}

// ---------------------------------------------------------------------------
// Fallback (ws too small): round-2 fused kernel (258us known-good).
// ---------------------------------------------------------------------------
__global__ __launch_bounds__(256) void edge_fused(
    const float* __restrict__ edge, const float* __restrict__ nlen, const float* __restrict__ nang,
    const float* __restrict__ bq,   const float* __restrict__ bk2,  const float* __restrict__ bm2,
    const float* __restrict__ bc,
    const float* __restrict__ g_att, const float* __restrict__ b_att,
    const float* __restrict__ g_bn,  const float* __restrict__ b_bn,
    const short* __restrict__ wsm,  const float* __restrict__ wsb,
    float* __restrict__ out)
{
  __shared__ short smem[2*16384];
  const int lane = threadIdx.x & 63;
  const int wid  = threadIdx.x >> 6;
  int tile = blockIdx.x*4 + wid;
  if (tile > NTILES-1) tile = NTILES-1;
  const int g  = lane >> 4;
  const int er = lane & 15;
  const size_t e = (size_t)tile*16 + er;
  const float* erow = edge + e*128;

  stage_mat(wsm + 0*16384, smem, wid, lane);
  s8v BE[4];
  #pragma unroll
  for (int kk = 0; kk < 4; ++kk) BE[kk] = load_bfrag(erow + kk*32 + g*8);
  f4 acc[8], gm[8];
  s4v qb[8], ekb[8], emb[8], gateb[8];
  s8v S[4], BL[4], BA[4];
  #pragma unroll
  for (int mb = 0; mb < 8; ++mb){ f4 z = {0.f,0.f,0.f,0.f}; gm[mb] = z; }
  __syncthreads();

  stage_mat(wsm + 1*16384, smem + 16384, wid, lane);
  #pragma unroll
  for (int mb = 0; mb < 8; ++mb) acc[mb] = *(const f4*)(bq + mb*16 + g*4);
  mm8l(acc, BE, (const s8v*)smem, lane);
  #pragma unroll
  for (int mb = 0; mb < 8; ++mb){
    s4v t4; t4[0]=f2bf(acc[mb][0]); t4[1]=f2bf(acc[mb][1]); t4[2]=f2bf(acc[mb][2]); t4[3]=f2bf(acc[mb][3]);
    qb[mb] = t4;
  }
  __syncthreads();

  stage_mat(wsm + 2*16384, smem, wid, lane);
  #pragma unroll
  for (int mb = 0; mb < 8; ++mb){ f4 z = {0.f,0.f,0.f,0.f}; acc[mb] = z; }
  mm8l(acc, BE, (const s8v*)(smem + 16384), lane);
  #pragma unroll
  for (int mb = 0; mb < 8; ++mb){
    s4v t4; t4[0]=f2bf(acc[mb][0]); t4[1]=f2bf(acc[mb][1]); t4[2]=f2bf(acc[mb][2]); t4[3]=f2bf(acc[mb][3]);
    ekb[mb] = t4;
  }
  __syncthreads();

  stage_mat(wsm + 8*16384, smem + 16384, wid, lane);
  #pragma unroll
  for (int mb = 0; mb < 8; ++mb){ f4 z = {0.f,0.f,0.f,0.f}; acc[mb] = z; }
  mm8l(acc, BE, (const s8v*)smem, lane);
  #pragma unroll
  for (int mb = 0; mb < 8; ++mb){
    s4v t4; t4[0]=f2bf(acc[mb][0]); t4[1]=f2bf(acc[mb][1]); t4[2]=f2bf(acc[mb][2]); t4[3]=f2bf(acc[mb][3]);
    emb[mb] = t4;
  }
  {
    const float* lrow = nlen + e*3*128;
    const float* arow = nang + e*3*128;
    #pragma unroll
    for (int kk = 0; kk < 4; ++kk){
      BL[kk] = load_bfrag(lrow + kk*32 + g*8);
      BA[kk] = load_bfrag(arow + kk*32 + g*8);
    }
  }
  __syncthreads();

  int cur = 1;
  #pragma unroll 1
  for (int t = 0; t < 3; ++t){
    stage_mat(wsm + 3*16384, smem + (cur^1)*16384, wid, lane);
    #pragma unroll
    for (int mb = 0; mb < 8; ++mb){
      f4 b = *(const f4*)(wsb + t*128 + mb*16 + g*4);
      #pragma unroll
      for (int r = 0; r < 4; ++r) b[r] += bf2f(ekb[mb][r]);
      acc[mb] = b;
    }
    mm8l(acc, BL, (const s8v*)(smem + cur*16384), lane);
    __syncthreads(); cur ^= 1;

    stage_mat(wsm + 5*16384, smem + (cur^1)*16384, wid, lane);
    mm8l(acc, BA, (const s8v*)(smem + cur*16384), lane);
    #pragma unroll
    for (int kk = 0; kk < 4; ++kk){
      #pragma unroll
      for (int p = 0; p < 4; ++p){
        float x0 = acc[2*kk][p];   S[kk][p]   = f2bf(x0 * sigm(x0));
        float x1 = acc[2*kk+1][p]; S[kk][4+p] = f2bf(x1 * sigm(x1));
      }
    }
    __syncthreads(); cur ^= 1;

    stage_mat(wsm + (size_t)(11+t)*16384, smem + (cur^1)*16384, wid, lane);
    #pragma unroll
    for (int mb = 0; mb < 8; ++mb) acc[mb] = *(const f4*)(bk2 + mb*16 + g*4);
    mm8l(acc, S, (const s8v*)(smem + cur*16384), lane);
    {
      float sm = 0.f, ssq = 0.f;
      #pragma unroll
      for (int mb = 0; mb < 8; ++mb){
        #pragma unroll
        for (int r = 0; r < 4; ++r){
          float a = bf2f(qb[mb][r]) * acc[mb][r] * 0.08838834764831845f;
          acc[mb][r] = a; sm += a; ssq += a*a;
        }
      }
      sm  += __shfl_xor(sm, 16);  sm  += __shfl_xor(sm, 32);
      ssq += __shfl_xor(ssq, 16); ssq += __shfl_xor(ssq, 32);
      float mean = sm * (1.f/128.f);
      float rstd = rsqrtf(ssq * (1.f/128.f) - mean*mean + 1e-5f);
      #pragma unroll
      for (int mb = 0; mb < 8; ++mb){
        f4 ga = *(const f4*)(g_att + mb*16 + g*4);
        f4 bb = *(const f4*)(b_att + mb*16 + g*4);
        s4v t4;
        #pragma unroll
        for (int r = 0; r < 4; ++r)
          t4[r] = f2bf(sigm((acc[mb][r] - mean)*rstd*ga[r] + bb[r]));
        gateb[mb] = t4;
      }
    }
    __syncthreads(); cur ^= 1;

    stage_mat(wsm + 4*16384, smem + (cur^1)*16384, wid, lane);
    #pragma unroll
    for (int mb = 0; mb < 8; ++mb){
      f4 b = *(const f4*)(wsb + 384 + t*128 + mb*16 + g*4);
      #pragma unroll
      for (int r = 0; r < 4; ++r) b[r] += bf2f(emb[mb][r]);
      acc[mb] = b;
    }
    mm8l(acc, BL, (const s8v*)(smem + cur*16384), lane);
    __syncthreads(); cur ^= 1;

    stage_mat(wsm + 6*16384, smem + (cur^1)*16384, wid, lane);
    mm8l(acc, BA, (const s8v*)(smem + cur*16384), lane);
    #pragma unroll
    for (int kk = 0; kk < 4; ++kk){
      #pragma unroll
      for (int p = 0; p < 4; ++p){
        float x0 = acc[2*kk][p];   S[kk][p]   = f2bf(x0 * sigm(x0));
        float x1 = acc[2*kk+1][p]; S[kk][4+p] = f2bf(x1 * sigm(x1));
      }
    }
    __syncthreads(); cur ^= 1;

    stage_mat(wsm + (size_t)(t < 2 ? 9 + t : 7)*16384, smem + (cur^1)*16384, wid, lane);
    #pragma unroll
    for (int mb = 0; mb < 8; ++mb) acc[mb] = *(const f4*)(bm2 + mb*16 + g*4);
    mm8l(acc, S, (const s8v*)(smem + cur*16384), lane);
    if (t < 2){
      const float* lrow = nlen + (e*3 + t + 1)*128;
      const float* arow = nang + (e*3 + t + 1)*128;
      #pragma unroll
      for (int kk = 0; kk < 4; ++kk){
        BL[kk] = load_bfrag(lrow + kk*32 + g*8);
        BA[kk] = load_bfrag(arow + kk*32 + g*8);
      }
    }
    #pragma unroll
    for (int mb = 0; mb < 8; ++mb){
      #pragma unroll
      for (int r = 0; r < 4; ++r) gm[mb][r] += acc[mb][r] * bf2f(gateb[mb][r]);
    }
    __syncthreads(); cur ^= 1;
  }

  s8v GF[4];
  #pragma unroll
  for (int kk = 0; kk < 4; ++kk){
    #pragma unroll
    for (int p = 0; p < 4; ++p){
      GF[kk][p]   = f2bf(gm[2*kk][p]);
      GF[kk][4+p] = f2bf(gm[2*kk+1][p]);
    }
  }
  #pragma unroll
  for (int mb = 0; mb < 8; ++mb){
    f4 b = *(const f4*)(bc + mb*16 + g*4);
    #pragma unroll
    for (int r = 0; r < 4; ++r) b[r] *= 3.f;
    acc[mb] = b;
  }
  mm8l(acc, GF, (const s8v*)(smem + cur*16384), lane);

  float sm = 0.f, ssq = 0.f;
  #pragma unroll
  for (int mb = 0; mb < 8; ++mb){
    #pragma unroll
    for (int r = 0; r < 4; ++r){ sm += acc[mb][r]; ssq += acc[mb][r]*acc[mb][r]; }
  }
  sm  += __shfl_xor(sm, 16);  sm  += __shfl_xor(sm, 32);
  ssq += __shfl_xor(ssq, 16); ssq += __shfl_xor(ssq, 32);
  float mean = sm * (1.f/128.f);
  float rstd = rsqrtf(ssq * (1.f/128.f) - mean*mean + 1e-5f);

  #pragma unroll
  for (int mb = 0; mb < 8; ++mb){
    f4 ev  = *(const f4*)(erow + mb*16 + g*4);
    f4 gv  = *(const f4*)(g_bn + mb*16 + g*4);
    f4 bv2 = *(const f4*)(b_bn + mb*16 + g*4);
    f4 o;
    #pragma unroll
    for (int r = 0; r < 4; ++r){
      float x = ev[r] + (acc[mb][r] - mean)*rstd*gv[r] + bv2[r];
      o[r] = (x > 20.f) ? x : log1pf(__expf(x));
    }
    *(f4*)(out + e*128 + mb*16 + g*4) = o;
  }
}

extern "C" void kernel_launch(void* const* d_in, const int* in_sizes, int n_in,
                              void* d_out, int out_size, void* d_ws, size_t ws_size,
                              hipStream_t stream)
{
  const float* edge = (const float*)d_in[0];
  const float* nlen = (const float*)d_in[1];
  const float* nang = (const float*)d_in[2];
  const float* Wq  = (const float*)d_in[3];
  const float* bq  = (const float*)d_in[4];
  const float* Wk  = (const float*)d_in[5];
  const float* bk  = (const float*)d_in[6];
  const float* Wv  = (const float*)d_in[7];
  const float* bv  = (const float*)d_in[8];
  const float* Wke = (const float*)d_in[9];
  const float* bke = (const float*)d_in[10];
  const float* Wve = (const float*)d_in[11];
  const float* bve = (const float*)d_in[12];
  const float* We  = (const float*)d_in[13];
  const float* Wc  = (const float*)d_in[14];
  const float* bc  = (const float*)d_in[15];
  const float* Wk1 = (const float*)d_in[16];
  const float* bk1 = (const float*)d_in[17];
  const float* Wk2 = (const float*)d_in[18];
  const float* bk2 = (const float*)d_in[19];
  const float* Wm1 = (const float*)d_in[20];
  const float* bm1 = (const float*)d_in[21];
  const float* Wm2 = (const float*)d_in[22];
  const float* bm2 = (const float*)d_in[23];
  const float* g_att = (const float*)d_in[24];
  const float* b_att = (const float*)d_in[25];
  const float* g_bn  = (const float*)d_in[26];
  const float* b_bn  = (const float*)d_in[27];

  short* wsm = (short*)d_ws;
  float* wsb = (float*)((char*)d_ws + 458752);
  char*  ws  = (char*)d_ws;

  pack_weights<<<dim3(14*64), dim3(256), 0, stream>>>(
      Wq, Wk, Wv, Wke, Wve, We, Wc, Wk1, Wk2, Wm1, Wm2, wsm);
  make_biases<<<dim3(6), dim3(128), 0, stream>>>(
      bk, bke, bk1, bv, bve, bm1, Wk1, Wm1, wsb);

  if (ws_size >= WS_NEED){
    k_proj<<<dim3(512), dim3(256), 0, stream>>>(edge, wsm, ws);
    k_mid<<<dim3(170, 3), dim3(256), 0, stream>>>(nlen, nang, wsm, wsb, ws);
    k_fin<<<dim3(512), dim3(256), 0, stream>>>(
        edge, bq, bk2, bm2, bc, g_att, b_att, g_bn, b_bn, wsm, ws, (float*)d_out);
  } else {
    edge_fused<<<dim3((NTILES + 3)/4), dim3(256), 0, stream>>>(
        edge, nlen, nang, bq, bk2, bm2, bc, g_att, b_att, g_bn, b_bn,
        wsm, wsb, (float*)d_out);
  }
}

// Round 7
// 257.270 us; speedup vs baseline: 7.1779x; 7.1779x over previous
//
#include <hip/hip_runtime.h>

#define E_TOTAL 50000
#define NTILES  3125      // E_TOTAL / 16, exact
#define NPAIR   1563      // ceil(NTILES / 2) -- one 32-edge block per pair

typedef float f4  __attribute__((ext_vector_type(4)));
typedef short s8v __attribute__((ext_vector_type(8)));   // 8 bf16 bit-patterns (4 VGPRs)
typedef short s4v __attribute__((ext_vector_type(4)));   // 4 bf16 bit-patterns (2 VGPRs)

typedef __attribute__((address_space(3))) unsigned lds_u32;
typedef __attribute__((address_space(1))) const unsigned g_u32;

__device__ __forceinline__ short f2bf(float x){
  unsigned u = __builtin_bit_cast(unsigned, x);
  u += 0x7fffu + ((u >> 16) & 1u);           // RNE
  return (short)(u >> 16);
}
__device__ __forceinline__ float bf2f(short s){
  unsigned u = ((unsigned)(unsigned short)s) << 16;
  return __builtin_bit_cast(float, u);
}
__device__ __forceinline__ float sigm(float x){ return 1.f/(1.f + __expf(-x)); }

// Half-phase boundary: wait own stage loads + LDS ops, 2-wave barrier.
__device__ __forceinline__ void vmbar(){
  asm volatile("s_waitcnt vmcnt(0) lgkmcnt(0)" ::: "memory");
  __builtin_amdgcn_s_barrier();
}

__device__ __forceinline__ s8v load_bfrag(const float* p){
  f4 a = *(const f4*)p;
  f4 b = *(const f4*)(p + 4);
  s8v r;
  r[0]=f2bf(a[0]); r[1]=f2bf(a[1]); r[2]=f2bf(a[2]); r[3]=f2bf(a[3]);
  r[4]=f2bf(b[0]); r[5]=f2bf(b[1]); r[6]=f2bf(b[2]); r[7]=f2bf(b[3]);
  return r;
}

// Half-matrix GEMM: D[64 feats x 16 edges] += A(16KB LDS half) @ B
__device__ __forceinline__ void mm4(f4* a4, const s8v* B, const short* Ab, int lane){
  const s8v* A = (const s8v*)Ab;
  #pragma unroll
  for (int mb = 0; mb < 4; ++mb){
    #pragma unroll
    for (int kk = 0; kk < 4; ++kk){
      s8v af = A[(mb*4 + kk)*64 + lane];
      a4[mb] = __builtin_amdgcn_mfma_f32_16x16x32_bf16(af, B[kk], a4[mb], 0, 0, 0);
    }
  }
}

// Stage one 16KB matrix-half: 2 waves x 8 instrs x 1KB, global->LDS direct.
__device__ __forceinline__ void stage_half(const short* __restrict__ src,
                                           short* dst, int wid, int lane){
  #pragma unroll
  for (int j = 0; j < 8; ++j){
    const short* gsrc = src + wid*4096 + j*512 + lane*8;
    short* ldst = dst + wid*4096 + j*512;       // wave-uniform base
    __builtin_amdgcn_global_load_lds((g_u32*)(const void*)gsrc, (lds_u32*)(void*)ldst, 16, 0, 0);
  }
}

__device__ __forceinline__ void zero4(f4* a){
  #pragma unroll
  for (int mb = 0; mb < 4; ++mb){ f4 z = {0.f,0.f,0.f,0.f}; a[mb] = z; }
}
__device__ __forceinline__ void initb(f4* a, const float* Pb, int g){
  #pragma unroll
  for (int mb = 0; mb < 4; ++mb) a[mb] = *(const f4*)(Pb + mb*16 + g*4);
}
__device__ __forceinline__ void initc(f4* a, const float* Pb, const s4v* carry, int g){
  #pragma unroll
  for (int mb = 0; mb < 4; ++mb){
    f4 b = *(const f4*)(Pb + mb*16 + g*4);
    #pragma unroll
    for (int r = 0; r < 4; ++r) b[r] += bf2f(carry[mb][r]);
    a[mb] = b;
  }
}
__device__ __forceinline__ void cvt4x(s4v* d, const f4* a){
  #pragma unroll
  for (int mb = 0; mb < 4; ++mb){
    s4v t; t[0]=f2bf(a[mb][0]); t[1]=f2bf(a[mb][1]); t[2]=f2bf(a[mb][2]); t[3]=f2bf(a[mb][3]);
    d[mb] = t;
  }
}
__device__ __forceinline__ void silu2(s8v& S, const f4& x0, const f4& x1){
  #pragma unroll
  for (int p = 0; p < 4; ++p){
    float a = x0[p]; S[p]   = f2bf(a * sigm(a));
    float b = x1[p]; S[4+p] = f2bf(b * sigm(b));
  }
}

// ---------------------------------------------------------------------------
// Precompute: 14 fragment-ready bf16 A-matrices (A[m][k] = W[k][m], optionally
// W = X@Y fused product), packed so lane reads 16B contiguous per (mblk,kk).
//   mi 0 WqT(nat) | 1 GKT=Wk@Wk1a | 2 GMT=Wv@Wm1a | 3 GKaT=We@Wk1c | 4 GMaT=We@Wm1c
//   mi 5 Wk2T(dlay) | 6 Wm2T(dlay) | 7 WcT(dlay) | 8..10 GKeT[t] | 11..13 GMeT[t]
// ---------------------------------------------------------------------------
__global__ __launch_bounds__(256) void pack_weights(
    const float* __restrict__ Wq, const float* __restrict__ Wk, const float* __restrict__ Wv,
    const float* __restrict__ Wke, const float* __restrict__ Wve, const float* __restrict__ We,
    const float* __restrict__ Wc, const float* __restrict__ Wk1, const float* __restrict__ Wk2,
    const float* __restrict__ Wm1, const float* __restrict__ Wm2,
    short* __restrict__ wsm)
{
  int mi   = blockIdx.x >> 6;
  int elem = ((blockIdx.x & 63) << 8) + threadIdx.x;   // 0..16383
  int p  = elem & 7;
  int l  = (elem >> 3) & 63;
  int kk = (elem >> 9) & 3;
  int mb = elem >> 11;
  int gg = l >> 4;
  int m  = mb*16 + (l & 15);
  bool dlay = (mi == 5) || (mi == 6) || (mi == 7);
  int k = dlay ? (kk*32 + ((p < 4) ? (gg*4 + p) : (16 + gg*4 + (p - 4))))
               : (kk*32 + gg*8 + p);

  const float* X = nullptr; const float* Y = nullptr; const float* W = nullptr;
  switch (mi){
    case 0: W = Wq; break;
    case 1: X = Wk; Y = Wk1;            break;
    case 2: X = Wv; Y = Wm1;            break;
    case 3: X = We; Y = Wk1 + 256*128;  break;
    case 4: X = We; Y = Wm1 + 256*128;  break;
    case 5: W = Wk2; break;
    case 6: W = Wm2; break;
    case 7: W = Wc;  break;
    default:
      if (mi < 11){ X = Wke + (mi-8)*16384;  Y = Wk1 + 128*128; }
      else        { X = Wve + (mi-11)*16384; Y = Wm1 + 128*128; }
  }
  float v;
  if (W){
    v = W[k*128 + m];
  } else {
    v = 0.f;
    for (int j = 0; j < 128; ++j) v += X[k*128 + j] * Y[j*128 + m];
  }
  wsm[(size_t)mi*16384 + elem] = f2bf(v);
}

// biasK[t] = bk@Wk1a + bke[t]@Wk1b + bk1 ; biasM[t] = bv@Wm1a + bve[t]@Wm1b + bm1
__global__ __launch_bounds__(128) void make_biases(
    const float* __restrict__ bk,  const float* __restrict__ bke, const float* __restrict__ bk1,
    const float* __restrict__ bv,  const float* __restrict__ bve, const float* __restrict__ bm1,
    const float* __restrict__ Wk1, const float* __restrict__ Wm1,
    float* __restrict__ wsb)
{
  int b = blockIdx.x;          // 0..2 -> biasK[t], 3..5 -> biasM[t]
  int t = b % 3;
  bool isM = b >= 3;
  int o = threadIdx.x;
  const float* W  = isM ? Wm1 : Wk1;
  const float* b0 = isM ? bv  : bk;
  const float* be = (isM ? bve : bke) + t*128;
  const float* b1 = isM ? bm1 : bk1;
  float v = b1[o];
  for (int j = 0; j < 128; ++j)
    v += b0[j]*W[j*128 + o] + be[j]*W[(128 + j)*128 + o];
  wsb[b*128 + o] = v;
}

// ---------------------------------------------------------------------------
// Main fused kernel. 2 waves/block (32 edges), LDS = 2x16KB half-matrix
// double buffer + 7KB params = 39.9KB -> 4 blocks/CU (8 waves/CU).
// 44 half-phases: { stage(next half) ; compute(cur half) ; vmcnt0 ; 2-wave
// barrier }. Stage latency hides under compute; waves of different blocks
// are fully independent (no convoy).
// P layout (floats): 0 biasK[3x128] | 384 biasM | 768 bq | 896 bk2 |
//   1024 bm2 | 1152 3*bc | 1280 g_att | 1408 b_att | 1536 g_bn | 1664 b_bn
// ---------------------------------------------------------------------------
__global__ __launch_bounds__(128) void edge_main(
    const float* __restrict__ edge, const float* __restrict__ nlen, const float* __restrict__ nang,
    const float* __restrict__ bq,   const float* __restrict__ bk2,  const float* __restrict__ bm2,
    const float* __restrict__ bc,
    const float* __restrict__ g_att, const float* __restrict__ b_att,
    const float* __restrict__ g_bn,  const float* __restrict__ b_bn,
    const short* __restrict__ wsm,  const float* __restrict__ wsb,
    float* __restrict__ out)
{
  __shared__ short smem[19968];          // 39936 B
  short* B0 = smem;                      // lo-half buffer (16KB)
  short* B1 = smem + 8192;               // hi-half buffer (16KB)
  float* P  = (float*)(smem + 16384);    // 7KB params

  const int lane = threadIdx.x & 63;
  const int wid  = threadIdx.x >> 6;
  const int g = lane >> 4, er = lane & 15;
  int tile = blockIdx.x*2 + wid;
  if (tile > NTILES-1) tile = NTILES-1;  // last pair: both waves do tile 3124 (identical -> benign)
  const size_t e = (size_t)tile*16 + er;
  const float* erow = edge + e*128;

  // ---- prologue: stage Wq.lo ; params -> LDS ; edge fragments ----
  stage_half(wsm + 0*16384, B0, wid, lane);
  {
    const int tx = threadIdx.x;
    P[768  + tx] = bq[tx];
    P[896  + tx] = bk2[tx];
    P[1024 + tx] = bm2[tx];
    P[1152 + tx] = 3.f*bc[tx];
    P[1280 + tx] = g_att[tx];
    P[1408 + tx] = b_att[tx];
    P[1536 + tx] = g_bn[tx];
    P[1664 + tx] = b_bn[tx];
    #pragma unroll
    for (int j = 0; j < 3; ++j){
      P[j*128 + tx]       = wsb[j*128 + tx];
      P[384 + j*128 + tx] = wsb[384 + j*128 + tx];
    }
  }
  s8v BE[4];
  #pragma unroll
  for (int kk = 0; kk < 4; ++kk) BE[kk] = load_bfrag(erow + kk*32 + g*8);

  f4 aL[4], aH[4], gm[8];
  s4v qb[8], ekb[8], emb[8], gateb[8];
  s8v S[4], BL[4], BA[4];

  vmbar();

  // p0: Wq -> qb
  stage_half(wsm + 0*16384 + 8192, B1, wid, lane);
  initb(aL, P + 768, g);
  mm4(aL, BE, B0, lane);
  vmbar();
  stage_half(wsm + 1*16384, B0, wid, lane);          // GK.lo
  initb(aH, P + 768 + 64, g);
  mm4(aH, BE, B1, lane);
  cvt4x(qb, aL); cvt4x(qb + 4, aH);
  vmbar();

  // p1: GK -> ekb
  stage_half(wsm + 1*16384 + 8192, B1, wid, lane);
  zero4(aL); mm4(aL, BE, B0, lane);
  vmbar();
  stage_half(wsm + 2*16384, B0, wid, lane);          // GM.lo
  zero4(aH); mm4(aH, BE, B1, lane);
  cvt4x(ekb, aL); cvt4x(ekb + 4, aH);
  vmbar();

  // p2: GM -> emb ; issue BL/BA(t=0)
  stage_half(wsm + 2*16384 + 8192, B1, wid, lane);
  {
    const float* lrow = nlen + e*3*128;
    const float* arow = nang + e*3*128;
    #pragma unroll
    for (int kk = 0; kk < 4; ++kk){
      BL[kk] = load_bfrag(lrow + kk*32 + g*8);
      BA[kk] = load_bfrag(arow + kk*32 + g*8);
    }
  }
  zero4(aL); mm4(aL, BE, B0, lane);
  vmbar();
  stage_half(wsm + 8*16384, B0, wid, lane);          // GKe0.lo
  zero4(aH); mm4(aH, BE, B1, lane);
  cvt4x(emb, aL); cvt4x(emb + 4, aH);
  vmbar();

  #pragma unroll
  for (int mb = 0; mb < 8; ++mb){ f4 z = {0.f,0.f,0.f,0.f}; gm[mb] = z; }

  #pragma unroll 1
  for (int t = 0; t < 3; ++t){
    const short* GKe = wsm + (size_t)(8 + t)*16384;
    const short* GMe = wsm + (size_t)(11 + t)*16384;
    const short* NXT = (t < 2) ? wsm + (size_t)(9 + t)*16384 : wsm + (size_t)7*16384;

    // pA: GKe[t] (B=BL), acc = biasK[t] + ekb
    stage_half(GKe + 8192, B1, wid, lane);
    initc(aL, P + t*128, ekb, g);
    mm4(aL, BL, B0, lane);
    vmbar();
    stage_half(wsm + 3*16384, B0, wid, lane);        // GKa.lo
    initc(aH, P + t*128 + 64, ekb + 4, g);
    mm4(aH, BL, B1, lane);
    vmbar();

    // pB: GKa (B=BA) ; silu -> S
    stage_half(wsm + 3*16384 + 8192, B1, wid, lane);
    mm4(aL, BA, B0, lane);
    silu2(S[0], aL[0], aL[1]);
    silu2(S[1], aL[2], aL[3]);
    vmbar();
    stage_half(wsm + 5*16384, B0, wid, lane);        // Wk2.lo
    mm4(aH, BA, B1, lane);
    silu2(S[2], aH[0], aH[1]);
    silu2(S[3], aH[2], aH[3]);
    vmbar();

    // pC: Wk2 (B=S) -> alpha ; LN ; gate
    stage_half(wsm + 5*16384 + 8192, B1, wid, lane);
    initb(aL, P + 896, g);
    mm4(aL, S, B0, lane);
    vmbar();
    stage_half(GMe, B0, wid, lane);                  // GMe.lo
    initb(aH, P + 896 + 64, g);
    mm4(aH, S, B1, lane);
    {
      float sm = 0.f, ssq = 0.f;
      #pragma unroll
      for (int mb = 0; mb < 4; ++mb){
        #pragma unroll
        for (int r = 0; r < 4; ++r){
          float a = bf2f(qb[mb][r]) * aL[mb][r] * 0.08838834764831845f;
          aL[mb][r] = a; sm += a; ssq += a*a;
          float b2 = bf2f(qb[4+mb][r]) * aH[mb][r] * 0.08838834764831845f;
          aH[mb][r] = b2; sm += b2; ssq += b2*b2;
        }
      }
      sm  += __shfl_xor(sm, 16);  sm  += __shfl_xor(sm, 32);
      ssq += __shfl_xor(ssq, 16); ssq += __shfl_xor(ssq, 32);
      float mean = sm * (1.f/128.f);
      float rstd = rsqrtf(ssq * (1.f/128.f) - mean*mean + 1e-5f);
      #pragma unroll
      for (int mb = 0; mb < 4; ++mb){
        f4 ga = *(const f4*)(P + 1280 + mb*16 + g*4);
        f4 bb = *(const f4*)(P + 1408 + mb*16 + g*4);
        f4 gh = *(const f4*)(P + 1280 + 64 + mb*16 + g*4);
        f4 bh = *(const f4*)(P + 1408 + 64 + mb*16 + g*4);
        s4v lo4, hi4;
        #pragma unroll
        for (int r = 0; r < 4; ++r){
          lo4[r] = f2bf(sigm((aL[mb][r] - mean)*rstd*ga[r] + bb[r]));
          hi4[r] = f2bf(sigm((aH[mb][r] - mean)*rstd*gh[r] + bh[r]));
        }
        gateb[mb] = lo4; gateb[4+mb] = hi4;
      }
    }
    vmbar();

    // pD: GMe[t] (B=BL), acc = biasM[t] + emb
    stage_half(GMe + 8192, B1, wid, lane);
    initc(aL, P + 384 + t*128, emb, g);
    mm4(aL, BL, B0, lane);
    vmbar();
    stage_half(wsm + 4*16384, B0, wid, lane);        // GMa.lo
    initc(aH, P + 384 + t*128 + 64, emb + 4, g);
    mm4(aH, BL, B1, lane);
    vmbar();

    // pE: GMa (B=BA) ; silu -> S
    stage_half(wsm + 4*16384 + 8192, B1, wid, lane);
    mm4(aL, BA, B0, lane);
    silu2(S[0], aL[0], aL[1]);
    silu2(S[1], aL[2], aL[3]);
    vmbar();
    stage_half(wsm + 6*16384, B0, wid, lane);        // Wm2.lo
    mm4(aH, BA, B1, lane);
    silu2(S[2], aH[0], aH[1]);
    silu2(S[3], aH[2], aH[3]);
    vmbar();

    // pF: Wm2 (B=S) ; gm += gate*acc ; stage NXT.lo ; prefetch BL/BA(t+1)
    stage_half(wsm + 6*16384 + 8192, B1, wid, lane);
    initb(aL, P + 1024, g);
    mm4(aL, S, B0, lane);
    vmbar();
    stage_half(NXT, B0, wid, lane);
    if (t < 2){
      const float* lrow = nlen + (e*3 + t + 1)*128;
      const float* arow = nang + (e*3 + t + 1)*128;
      #pragma unroll
      for (int kk = 0; kk < 4; ++kk){
        BL[kk] = load_bfrag(lrow + kk*32 + g*8);
        BA[kk] = load_bfrag(arow + kk*32 + g*8);
      }
    }
    initb(aH, P + 1024 + 64, g);
    mm4(aH, S, B1, lane);
    #pragma unroll
    for (int mb = 0; mb < 4; ++mb){
      #pragma unroll
      for (int r = 0; r < 4; ++r){
        gm[mb][r]   += aL[mb][r] * bf2f(gateb[mb][r]);
        gm[4+mb][r] += aH[mb][r] * bf2f(gateb[4+mb][r]);
      }
    }
    vmbar();
  }

  // pG: Wc (B0 = Wc.lo, staged in last pF) ; LN ; softplus(edge + .) ; store
  stage_half(wsm + 7*16384 + 8192, B1, wid, lane);
  f4 ev[8];
  #pragma unroll
  for (int mb = 0; mb < 8; ++mb) ev[mb] = *(const f4*)(erow + mb*16 + g*4);
  s8v GF[4];
  #pragma unroll
  for (int kk = 0; kk < 4; ++kk){
    #pragma unroll
    for (int p = 0; p < 4; ++p){
      GF[kk][p]   = f2bf(gm[2*kk][p]);
      GF[kk][4+p] = f2bf(gm[2*kk+1][p]);
    }
  }
  initb(aL, P + 1152, g);
  mm4(aL, GF, B0, lane);
  vmbar();
  initb(aH, P + 1152 + 64, g);
  mm4(aH, GF, B1, lane);

  float sm = 0.f, ssq = 0.f;
  #pragma unroll
  for (int mb = 0; mb < 4; ++mb){
    #pragma unroll
    for (int r = 0; r < 4; ++r){
      sm += aL[mb][r]; ssq += aL[mb][r]*aL[mb][r];
      sm += aH[mb][r]; ssq += aH[mb][r]*aH[mb][r];
    }
  }
  sm  += __shfl_xor(sm, 16);  sm  += __shfl_xor(sm, 32);
  ssq += __shfl_xor(ssq, 16); ssq += __shfl_xor(ssq, 32);
  float mean = sm * (1.f/128.f);
  float rstd = rsqrtf(ssq * (1.f/128.f) - mean*mean + 1e-5f);

  #pragma unroll
  for (int mb = 0; mb < 4; ++mb){
    f4 gv = *(const f4*)(P + 1536 + mb*16 + g*4);
    f4 bv = *(const f4*)(P + 1664 + mb*16 + g*4);
    f4 gv2= *(const f4*)(P + 1536 + 64 + mb*16 + g*4);
    f4 bv2= *(const f4*)(P + 1664 + 64 + mb*16 + g*4);
    f4 o1, o2;
    #pragma unroll
    for (int r = 0; r < 4; ++r){
      float x = ev[mb][r]   + (aL[mb][r] - mean)*rstd*gv[r]  + bv[r];
      o1[r] = (x > 20.f) ? x : log1pf(__expf(x));
      float y = ev[4+mb][r] + (aH[mb][r] - mean)*rstd*gv2[r] + bv2[r];
      o2[r] = (y > 20.f) ? y : log1pf(__expf(y));
    }
    *(f4*)(out + e*128 + mb*16 + g*4)      = o1;
    *(f4*)(out + e*128 + 64 + mb*16 + g*4) = o2;
  }
}

extern "C" void kernel_launch(void* const* d_in, const int* in_sizes, int n_in,
                              void* d_out, int out_size, void* d_ws, size_t ws_size,
                              hipStream_t stream)
{
  const float* edge = (const float*)d_in[0];
  const float* nlen = (const float*)d_in[1];
  const float* nang = (const float*)d_in[2];
  const float* Wq  = (const float*)d_in[3];
  const float* bq  = (const float*)d_in[4];
  const float* Wk  = (const float*)d_in[5];
  const float* bk  = (const float*)d_in[6];
  const float* Wv  = (const float*)d_in[7];
  const float* bv  = (const float*)d_in[8];
  const float* Wke = (const float*)d_in[9];
  const float* bke = (const float*)d_in[10];
  const float* Wve = (const float*)d_in[11];
  const float* bve = (const float*)d_in[12];
  const float* We  = (const float*)d_in[13];
  const float* Wc  = (const float*)d_in[14];
  const float* bc  = (const float*)d_in[15];
  const float* Wk1 = (const float*)d_in[16];
  const float* bk1 = (const float*)d_in[17];
  const float* Wk2 = (const float*)d_in[18];
  const float* bk2 = (const float*)d_in[19];
  const float* Wm1 = (const float*)d_in[20];
  const float* bm1 = (const float*)d_in[21];
  const float* Wm2 = (const float*)d_in[22];
  const float* bm2 = (const float*)d_in[23];
  const float* g_att = (const float*)d_in[24];
  const float* b_att = (const float*)d_in[25];
  const float* g_bn  = (const float*)d_in[26];
  const float* b_bn  = (const float*)d_in[27];

  // ws layout: 14 packed bf16 matrices (16384 shorts each) + 6*128 f32 biases
  short* wsm = (short*)d_ws;
  float* wsb = (float*)((char*)d_ws + (size_t)14*16384*2);

  pack_weights<<<dim3(14*64), dim3(256), 0, stream>>>(
      Wq, Wk, Wv, Wke, Wve, We, Wc, Wk1, Wk2, Wm1, Wm2, wsm);
  make_biases<<<dim3(6), dim3(128), 0, stream>>>(
      bk, bke, bk1, bv, bve, bm1, Wk1, Wm1, wsb);
  edge_main<<<dim3(NPAIR), dim3(128), 0, stream>>>(
      edge, nlen, nang, bq, bk2, bm2, bc, g_att, b_att, g_bn, b_bn,
      wsm, wsb, (float*)d_out);
}